// Round 9
// baseline (266.019 us; speedup 1.0000x reference)
//
#include <hip/hip_runtime.h>
#include <hip/hip_bf16.h>
#include <cstdint>

typedef __bf16 bf16;
typedef __bf16 bf16x8 __attribute__((ext_vector_type(8)));
typedef __bf16 bf16x4 __attribute__((ext_vector_type(4)));
typedef float f32x4 __attribute__((ext_vector_type(4)));

__device__ inline bf16x8 cvt8(const float* __restrict__ p) {
  float4 a = *(const float4*)p;
  float4 b = *(const float4*)(p + 4);
  bf16x8 r;
  r[0] = (bf16)a.x; r[1] = (bf16)a.y; r[2] = (bf16)a.z; r[3] = (bf16)a.w;
  r[4] = (bf16)b.x; r[5] = (bf16)b.y; r[6] = (bf16)b.z; r[7] = (bf16)b.w;
  return r;
}

// async global->LDS, 16B per lane; LDS dest = wave-uniform base + lane*16 (m97/m104)
__device__ inline void gl_lds16(const bf16* g, bf16* l) {
  auto gp = reinterpret_cast<const __attribute__((address_space(1))) uint32_t*>(
      reinterpret_cast<uintptr_t>(g));
  auto lp = reinterpret_cast<__attribute__((address_space(3))) uint32_t*>(
      reinterpret_cast<uintptr_t>(l));
  __builtin_amdgcn_global_load_lds(gp, lp, 16, 0, 0);
}

#define BAR() asm volatile("s_barrier" ::: "memory")

// ---------------------------------------------------------------- fused prep
__global__ __launch_bounds__(256) void prep_k(const float* __restrict__ x,
                                              bf16* __restrict__ xb,
                                              const float* __restrict__ wqkv,
                                              bf16* __restrict__ wqkvT,
                                              const float* __restrict__ wo,
                                              bf16* __restrict__ woT) {
  __shared__ bf16 T[32][33];
  const int bid = blockIdx.x;
  if (bid < 4096) {
    long i = ((long)bid * 256 + threadIdx.x) * 8;
    *(bf16x8*)(xb + i) = cvt8(x + i);
    return;
  }
  const float* in;
  bf16* out;
  int R, C, bx, by;
  if (bid < 7168) {
    int t = bid - 4096;
    in = wqkv; out = wqkvT; R = 1024; C = 3072;
    bx = t % 96; by = t / 96;
  } else {
    int t = bid - 7168;
    in = wo; out = woT; R = 1024; C = 1024;
    bx = t % 32; by = t / 32;
  }
  int tc = bx * 32, tr = by * 32;
  int c = threadIdx.x & 31, r8 = threadIdx.x >> 5;
#pragma unroll
  for (int i = 0; i < 4; i++) {
    int r = r8 + i * 8;
    T[r][c] = (bf16)in[(long)(tr + r) * C + tc + c];
  }
  __syncthreads();
#pragma unroll
  for (int i = 0; i < 4; i++) {
    int r = r8 + i * 8;
    out[(long)(tc + r) * R + tr + c] = T[c][r];
  }
}

// ---------------------------------------------------------------- 128x256 QKV GEMM (r6-proven)
// rotated pipeline: MFMA(frags kt) -> vmcnt(0) [STAGE(kt+1) issued one iter ago] ->
// ONE s_barrier -> ds_read frags(kt+1) -> STAGE(kt+2). 48KB LDS, 3 blocks/CU, grid 768.
// q-epilogue folds 8*log2(e) so attn uses exp2 with MFMA C-init bias (no per-elem sub).
__global__ __launch_bounds__(512, 4) void gemm256(const bf16* __restrict__ A,
                                                  const bf16* __restrict__ Bt,
                                                  const float* __restrict__ bias,
                                                  int K,
                                                  bf16* __restrict__ qb,
                                                  bf16* __restrict__ kb,
                                                  bf16* __restrict__ v4,
                                                  const float* __restrict__ qg,
                                                  const float* __restrict__ kg) {
  __shared__ __align__(16) bf16 As[2][4096];  // [buf][128 rows][32 cols] swizzled
  __shared__ __align__(16) bf16 Bs[2][8192];  // [buf][256 rows][32 cols] swizzled

  const int tid = threadIdx.x;
  const int lane = tid & 63;
  const int w = tid >> 6;
  const int quad = lane >> 4;
  const int l16 = lane & 15;
  const int wr = w >> 2;
  const int wc = w & 3;

  // bijective XCD swizzle (nwg = 768, %8 == 0)
  const int gx = gridDim.x;  // 12
  const int bid = blockIdx.y * gx + blockIdx.x;
  const int cpx = (gx * gridDim.y) >> 3;
  const int sw = (bid & 7) * cpx + (bid >> 3);
  const int n0 = (sw % gx) * 256;
  const int m0 = (sw / gx) * 128;

  const int srA = tid >> 2;                         // 0..127
  const int scS = ((tid & 3) ^ ((tid >> 3) & 3)) * 8;
  const bf16* aS = A + (long)(m0 + srA) * K + scS;
  const bf16* bS0 = Bt + (long)(n0 + srA) * K + scS;
  const bf16* bS1 = bS0 + (long)128 * K;

#define STAGE(tb, kt1)                                                   \
  {                                                                      \
    const long kc = (long)(kt1)*32;                                      \
    gl_lds16(aS + kc, &As[tb][w * 512]);                                 \
    gl_lds16(bS0 + kc, &Bs[tb][w * 512]);                                \
    gl_lds16(bS1 + kc, &Bs[tb][4096 + w * 512]);                         \
  }

  const int cphys = (quad ^ ((l16 >> 1) & 3)) * 8;
  const int aoff = (wr * 64 + l16) * 32 + cphys;
  const int boff = (wc * 64 + l16) * 32 + cphys;

#define LOADFRAGS(pb)                                                          \
  {                                                                            \
    _Pragma("unroll") for (int n = 0; n < 4; n++) bfr[n] =                     \
        *(const bf16x8*)&Bs[pb][boff + n * 512];                               \
    _Pragma("unroll") for (int m = 0; m < 4; m++) afr[m] =                     \
        *(const bf16x8*)&As[pb][aoff + m * 512];                               \
  }

  f32x4 acc[4][4];
#pragma unroll
  for (int i = 0; i < 4; i++)
#pragma unroll
    for (int j = 0; j < 4; j++) acc[i][j] = f32x4{0.f, 0.f, 0.f, 0.f};

  const int NK = K >> 5;  // 32
  bf16x8 afr[4], bfr[4];

  STAGE(0, 0);
  asm volatile("s_waitcnt vmcnt(0)" ::: "memory");
  BAR();
  LOADFRAGS(0);
  STAGE(1, 1);

  for (int kt = 0; kt < NK; ++kt) {
    __builtin_amdgcn_s_setprio(1);
#pragma unroll
    for (int m = 0; m < 4; m++)
#pragma unroll
      for (int n = 0; n < 4; n++)
        acc[m][n] = __builtin_amdgcn_mfma_f32_16x16x32_bf16(afr[m], bfr[n], acc[m][n], 0, 0, 0);
    __builtin_amdgcn_s_setprio(0);
    if (kt + 1 < NK) {
      asm volatile("s_waitcnt vmcnt(0)" ::: "memory");
      BAR();
      LOADFRAGS((kt + 1) & 1);
      if (kt + 2 < NK) STAGE(kt & 1, kt + 2);
    }
  }

  // ---------------- epilogue (m89/m91 C layout)
  const int which = n0 >> 10;  // 0=q, 1=k, 2=v
  if (which == 2) {
    const int T0 = (((m0 & 1023) + wr * 64) >> 2) + quad;
    const int bh = (m0 >> 10) * 16 + (((n0 + wc * 64) & 1023) >> 6);
#pragma unroll
    for (int m = 0; m < 4; m++) {
#pragma unroll
      for (int n = 0; n < 4; n++) {
        int ng = n0 + wc * 64 + n * 16 + l16;
        int dc = n * 16 + l16;
        float bj = bias[ng];
        bf16x4 pv;
#pragma unroll
        for (int r = 0; r < 4; r++) pv[r] = (bf16)(acc[m][n][r] + bj);
        *(bf16x4*)(v4 + ((long)bh * 16384 + (long)(T0 + m * 4) * 64 + dc) * 4) = pv;
      }
    }
    return;
  }

  const float* gg = which ? kg : qg;
  bf16* dst = which ? kb : qb;
  // q folds cos-sim scale * log2(e): attn computes p = exp2(st), bias in MFMA C-init
  const float fold = which ? 1.0f : 11.541560327111708f;
  const int h = ((n0 + wc * 64) & 1023) >> 6;
  const int bh = (m0 >> 10) * 16 + h;
  float bj[4], gain[4];
#pragma unroll
  for (int j = 0; j < 4; j++) {
    bj[j] = bias[n0 + wc * 64 + j * 16 + l16];
    gain[j] = gg[j * 16 + l16];
  }
  const float f = exp2f((float)l16 * (-13.287712379549449f / 16.0f));  // 10000^(-l16/16)

#pragma unroll
  for (int m = 0; m < 4; m++) {
#pragma unroll
    for (int r = 0; r < 4; r++) {
      int ntok = (m0 & 1023) + wr * 64 + m * 16 + quad * 4 + r;
      float v0 = acc[m][0][r] + bj[0];
      float v1 = acc[m][1][r] + bj[1];
      float v2 = acc[m][2][r] + bj[2];
      float v3 = acc[m][3][r] + bj[3];
      float ss = v0 * v0 + v1 * v1 + v2 * v2 + v3 * v3;
#pragma unroll
      for (int mk = 1; mk <= 8; mk <<= 1) ss += __shfl_xor(ss, mk, 64);
      float rms = rsqrtf(ss * (1.0f / 64.0f) + 1e-6f);
      v0 *= rms * gain[0]; v1 *= rms * gain[1]; v2 *= rms * gain[2]; v3 *= rms * gain[3];
      float sh, ch_, swv, cw;
      __sincosf((float)(ntok >> 5) * f, &sh, &ch_);
      __sincosf((float)(ntok & 31) * f, &swv, &cw);
      float w0 = v0 * ch_ - v2 * sh;
      float w1 = v1 * cw - v3 * swv;
      float w2 = v2 * ch_ + v0 * sh;
      float w3 = v3 * cw + v1 * swv;
      float nn = w0 * w0 + w1 * w1 + w2 * w2 + w3 * w3;
#pragma unroll
      for (int mk = 1; mk <= 8; mk <<= 1) nn += __shfl_xor(nn, mk, 64);
      float inv = rsqrtf(nn) * fold;
      long base = ((long)bh * 1024 + ntok) * 64 + l16;
      dst[base] = (bf16)(w0 * inv);
      dst[base + 16] = (bf16)(w1 * inv);
      dst[base + 32] = (bf16)(w2 * inv);
      dst[base + 48] = (bf16)(w3 * inv);
    }
  }
}

// ---------------------------------------------------------------- out-proj GEMM 128^2 (r6-proven)
__global__ __launch_bounds__(256, 4) void gemm_bt1(const bf16* __restrict__ A,
                                                   const bf16* __restrict__ Bt,
                                                   const float* __restrict__ bias,
                                                   int N, int K,
                                                   float* __restrict__ out) {
  __shared__ __align__(16) bf16 As[2][4096];  // [buf][128][32] swizzled
  __shared__ __align__(16) bf16 Bs[2][4096];

  const int tid = threadIdx.x;
  const int lane = tid & 63;
  const int w = tid >> 6;
  const int wm = (w & 1) * 64;
  const int wn = (w >> 1) * 64;
  const int quad = lane >> 4;
  const int l16 = lane & 15;

  const int m0 = blockIdx.y * 128;
  const int n0 = blockIdx.x * 128;

  int srow[2], scof[2];
#pragma unroll
  for (int l = 0; l < 2; l++) {
    int s = l * 256 + tid;
    srow[l] = s >> 2;
    scof[l] = ((s & 3) ^ ((s >> 3) & 3)) * 8;
  }

  auto stage = [&](int tb, int k0) {
    int hh = k0 >> 6;
#pragma unroll
    for (int l = 0; l < 2; l++) {
      int m1 = m0 + srow[l];
      int dc = (k0 & 63) + scof[l];
      const bf16* ga = A + ((long)((m1 >> 10) * 16 + hh) * 1024 + (m1 & 1023)) * 64 + dc;
      gl_lds16(ga, &As[tb][l * 2048 + w * 512]);
      gl_lds16(Bt + (long)(n0 + srow[l]) * K + k0 + scof[l], &Bs[tb][l * 2048 + w * 512]);
    }
  };

  const int cphys = (quad ^ ((l16 >> 1) & 3)) * 8;

  f32x4 acc[4][4];
#pragma unroll
  for (int i = 0; i < 4; i++)
#pragma unroll
    for (int j = 0; j < 4; j++) acc[i][j] = f32x4{0.f, 0.f, 0.f, 0.f};

  const int NK = K >> 5;  // 32
  bf16x8 af[4], bfr[4];

#define LOADFRAGS1(pb)                                                         \
  {                                                                            \
    _Pragma("unroll") for (int i = 0; i < 4; i++) {                            \
      af[i] = *(const bf16x8*)&As[pb][(wm + i * 16 + l16) * 32 + cphys];       \
      bfr[i] = *(const bf16x8*)&Bs[pb][(wn + i * 16 + l16) * 32 + cphys];      \
    }                                                                          \
  }

  stage(0, 0);
  asm volatile("s_waitcnt vmcnt(0)" ::: "memory");
  BAR();
  LOADFRAGS1(0);
  stage(1, 32);

  for (int kt = 0; kt < NK; ++kt) {
    __builtin_amdgcn_s_setprio(1);
#pragma unroll
    for (int i = 0; i < 4; i++)
#pragma unroll
      for (int j = 0; j < 4; j++)
        acc[i][j] = __builtin_amdgcn_mfma_f32_16x16x32_bf16(af[i], bfr[j], acc[i][j], 0, 0, 0);
    __builtin_amdgcn_s_setprio(0);
    if (kt + 1 < NK) {
      asm volatile("s_waitcnt vmcnt(0)" ::: "memory");
      BAR();
      LOADFRAGS1((kt + 1) & 1);
      if (kt + 2 < NK) stage(kt & 1, (kt + 2) << 5);
    }
  }

#pragma unroll
  for (int i = 0; i < 4; i++)
#pragma unroll
    for (int j = 0; j < 4; j++)
#pragma unroll
      for (int r = 0; r < 4; r++) {
        int mg = m0 + wm + i * 16 + quad * 4 + r;
        int ng = n0 + wn + j * 16 + l16;
        out[(long)mg * N + ng] = acc[i][j][r] + bias[ng];
      }
}

// ---------------------------------------------------------------- flash attention
// r9: XCD co-location — grid (x=bh=128, y=qchunk=8): the 8 blocks sharing one head's
// K/V have bid ≡ bh (mod 8) -> SAME XCD -> 7/8 of K/V traffic becomes L2-hit
// (r8 counters: FETCH 143MB = cross-XCD re-read; predicted ~55MB).
// VALU cuts (r8: VALUBusy 47% vs MfmaUtil 17%): softmax bias folded into MFMA C-init
// (deletes 64 v_sub/tile); denominator accumulated in f32x4 (4 parallel chains vs
// 16-deep serial dependent add chain).
__global__ __launch_bounds__(128, 2) void attn_k(bf16* __restrict__ qb,
                                                 const bf16* __restrict__ kb,
                                                 const bf16* __restrict__ v4) {
  __shared__ __align__(16) bf16 Ks[2][64][72];   // keys x d (padded, dbuf) 18KB
  __shared__ __align__(16) bf16 Vl[2][4096];     // linear v4 tile (dbuf)   16KB
  __shared__ __align__(16) bf16 Ps[2][16][72];   // per-wave P slot          4.6KB

  const int tid = threadIdx.x;   // 0..127
  const int lane = tid & 63;
  const int w = tid >> 6;        // 0..1
  const int quad = lane >> 4;
  const int l16 = lane & 15;

  const int bh = blockIdx.x;                    // co-location: bh fastest
  const int q0 = blockIdx.y * 128 + w * 64;

  const f32x4 NEGB = f32x4{-11.541560327111708f, -11.541560327111708f,
                           -11.541560327111708f, -11.541560327111708f};

  // Q fragments for 4 query groups (q already holds cos-sim scale * log2e)
  bf16x8 aq[4][2];
  long qrow[4];
#pragma unroll
  for (int g = 0; g < 4; g++) {
    qrow[g] = ((long)bh * 1024 + q0 + g * 16 + l16) * 64;
    aq[g][0] = *(const bf16x8*)(qb + qrow[g] + quad * 8);
    aq[g][1] = *(const bf16x8*)(qb + qrow[g] + 32 + quad * 8);
  }

  f32x4 o[4][4];
#pragma unroll
  for (int g = 0; g < 4; g++)
#pragma unroll
    for (int i = 0; i < 4; i++) o[g][i] = f32x4{0.f, 0.f, 0.f, 0.f};
  f32x4 lsv[4];
#pragma unroll
  for (int g = 0; g < 4; g++) lsv[g] = f32x4{0.f, 0.f, 0.f, 0.f};

  // K staging: 128 threads, 16 rows x 64 cols per pass, 4 passes
  const int sr = tid >> 3, sc = (tid & 7) * 8;
  const bf16* kbase = kb + (long)bh * 65536;
  const bf16* vbase = v4 + (long)bh * 65536;

  // prologue: stage tile 0 into buffer 0
  bf16x8 kr0 = *(const bf16x8*)(kbase + (long)sr * 64 + sc);
  bf16x8 kr1 = *(const bf16x8*)(kbase + (long)(sr + 16) * 64 + sc);
  bf16x8 kr2 = *(const bf16x8*)(kbase + (long)(sr + 32) * 64 + sc);
  bf16x8 kr3 = *(const bf16x8*)(kbase + (long)(sr + 48) * 64 + sc);
#pragma unroll
  for (int c = 0; c < 4; c++)
    gl_lds16(vbase + (w * 4 + c) * 512 + lane * 8, &Vl[0][(w * 4 + c) * 512]);
  asm volatile("s_waitcnt vmcnt(0)" ::: "memory");
  *(bf16x8*)&Ks[0][sr][sc] = kr0;
  *(bf16x8*)&Ks[0][sr + 16][sc] = kr1;
  *(bf16x8*)&Ks[0][sr + 32][sc] = kr2;
  *(bf16x8*)&Ks[0][sr + 48][sc] = kr3;
  asm volatile("s_waitcnt lgkmcnt(0)" ::: "memory");
  BAR();

  for (int kt = 0; kt < 1024; kt += 64) {
    const int cur = (kt >> 6) & 1;
    const bool pf = (kt + 64 < 1024);
    // issue next tile's staging loads (K -> regs, V -> alternate LDS buffer)
    if (pf) {
      kr0 = *(const bf16x8*)(kbase + (long)(kt + 64 + sr) * 64 + sc);
      kr1 = *(const bf16x8*)(kbase + (long)(kt + 64 + sr + 16) * 64 + sc);
      kr2 = *(const bf16x8*)(kbase + (long)(kt + 64 + sr + 32) * 64 + sc);
      kr3 = *(const bf16x8*)(kbase + (long)(kt + 64 + sr + 48) * 64 + sc);
#pragma unroll
      for (int c = 0; c < 4; c++)
        gl_lds16(vbase + (long)(kt + 64) * 64 + (w * 4 + c) * 512 + lane * 8,
                 &Vl[cur ^ 1][(w * 4 + c) * 512]);
    }

    // hoist K-frags and V-frags for this tile
    bf16x8 kf[4][2], vf[4][2];
#pragma unroll
    for (int i = 0; i < 4; i++) {
      kf[i][0] = *(const bf16x8*)&Ks[cur][i * 16 + l16][quad * 8];
      kf[i][1] = *(const bf16x8*)&Ks[cur][i * 16 + l16][32 + quad * 8];
      int D4 = (i * 16 + l16) * 4;
      bf16x4 a0 = *(const bf16x4*)&Vl[cur][quad * 512 + D4];
      bf16x4 a1 = *(const bf16x4*)&Vl[cur][quad * 512 + D4 + 256];
      bf16x4 a2 = *(const bf16x4*)&Vl[cur][quad * 512 + D4 + 2048];
      bf16x4 a3 = *(const bf16x4*)&Vl[cur][quad * 512 + D4 + 2048 + 256];
      vf[i][0] = __builtin_shufflevector(a0, a1, 0, 1, 2, 3, 4, 5, 6, 7);
      vf[i][1] = __builtin_shufflevector(a2, a3, 0, 1, 2, 3, 4, 5, 6, 7);
    }

    bf16x8 bp[2][2];
#pragma unroll
    for (int g = 0; g < 4; g++) {
      const int sl = g & 1;
      // St = K_tile · Qg^T + (-8*log2e)  [bias in C-init]; p = exp2(st)
#pragma unroll
      for (int i = 0; i < 4; i++) {
        f32x4 st = __builtin_amdgcn_mfma_f32_16x16x32_bf16(kf[i][0], aq[g][0], NEGB, 0, 0, 0);
        st = __builtin_amdgcn_mfma_f32_16x16x32_bf16(kf[i][1], aq[g][1], st, 0, 0, 0);
        bf16x4 pk;
#pragma unroll
        for (int r = 0; r < 4; r++) {
          float p = exp2f(st[r]);
          lsv[g][r] += p;                       // 4 independent chains, not 16-deep
          pk[r] = (bf16)p;
        }
        *(bf16x4*)&Ps[w][l16][i * 16 + quad * 4] = pk;
      }
      // same-wave DS is in-order: RAW safe, next group's stores can't pass these reads
      bp[sl][0] = *(const bf16x8*)&Ps[w][l16][quad * 8];
      bp[sl][1] = *(const bf16x8*)&Ps[w][l16][32 + quad * 8];
      if (g > 0) {
        const int pg = (g - 1) & 1;
#pragma unroll
        for (int i = 0; i < 4; i++) {
          o[g - 1][i] = __builtin_amdgcn_mfma_f32_16x16x32_bf16(vf[i][0], bp[pg][0], o[g - 1][i], 0, 0, 0);
          o[g - 1][i] = __builtin_amdgcn_mfma_f32_16x16x32_bf16(vf[i][1], bp[pg][1], o[g - 1][i], 0, 0, 0);
        }
      }
    }
    // pipeline drain: PV for group 3
#pragma unroll
    for (int i = 0; i < 4; i++) {
      o[3][i] = __builtin_amdgcn_mfma_f32_16x16x32_bf16(vf[i][0], bp[1][0], o[3][i], 0, 0, 0);
      o[3][i] = __builtin_amdgcn_mfma_f32_16x16x32_bf16(vf[i][1], bp[1][1], o[3][i], 0, 0, 0);
    }

    // commit next tile: wait K regs + V gl_lds (covered by the g-loop), write K to LDS
    if (pf) {
      asm volatile("s_waitcnt vmcnt(0)" ::: "memory");
      *(bf16x8*)&Ks[cur ^ 1][sr][sc] = kr0;
      *(bf16x8*)&Ks[cur ^ 1][sr + 16][sc] = kr1;
      *(bf16x8*)&Ks[cur ^ 1][sr + 32][sc] = kr2;
      *(bf16x8*)&Ks[cur ^ 1][sr + 48][sc] = kr3;
    }
    asm volatile("s_waitcnt lgkmcnt(0)" ::: "memory");
    BAR();
  }

#pragma unroll
  for (int g = 0; g < 4; g++) {
    float l = (lsv[g][0] + lsv[g][1]) + (lsv[g][2] + lsv[g][3]);
    l += __shfl_xor(l, 16, 64);
    l += __shfl_xor(l, 32, 64);
    float inv = 1.0f / l;
#pragma unroll
    for (int i = 0; i < 4; i++) {
      bf16x4 ov;
#pragma unroll
      for (int r = 0; r < 4; r++) ov[r] = (bf16)(o[g][i][r] * inv);
      *(bf16x4*)(qb + qrow[g] + i * 16 + quad * 4) = ov;
    }
  }
}

// ---------------------------------------------------------------- launcher
extern "C" void kernel_launch(void* const* d_in, const int* in_sizes, int n_in,
                              void* d_out, int out_size, void* d_ws, size_t ws_size,
                              hipStream_t stream) {
  (void)in_sizes; (void)n_in; (void)out_size; (void)ws_size;
  const float* x     = (const float*)d_in[0];
  const float* w_qkv = (const float*)d_in[1];
  const float* b_qkv = (const float*)d_in[2];
  const float* q_g   = (const float*)d_in[3];
  const float* k_g   = (const float*)d_in[4];
  const float* w_out = (const float*)d_in[5];
  const float* b_out = (const float*)d_in[6];
  float* out = (float*)d_out;

  char* ws = (char*)d_ws;
  bf16* wqkvT = (bf16*)ws; ws += (long)3072 * 1024 * 2;      // 6 MB
  bf16* woT   = (bf16*)ws; ws += (long)1024 * 1024 * 2;      // 2 MB
  bf16* xb    = (bf16*)ws; ws += (long)8192 * 1024 * 2;      // 16 MB
  bf16* qb    = (bf16*)ws; ws += (long)128 * 1024 * 64 * 2;  // 16 MB (q, then attention O)
  bf16* kb    = (bf16*)ws; ws += (long)128 * 1024 * 64 * 2;  // 16 MB
  bf16* v4    = (bf16*)ws; ws += (long)128 * 64 * 1024 * 2;  // 16 MB   (total 72 MB)

  prep_k<<<8192, 256, 0, stream>>>(x, xb, w_qkv, wqkvT, w_out, woT);
  gemm256<<<dim3(3072 / 256, 8192 / 128), 512, 0, stream>>>(xb, wqkvT, b_qkv, 1024,
                                                            qb, kb, v4, q_g, k_g);
  attn_k<<<dim3(128, 8), 128, 0, stream>>>(qb, kb, v4);
  gemm_bt1<<<dim3(1024 / 128, 8192 / 128), 256, 0, stream>>>(qb, woT, b_out,
                                                             1024, 1024, out);
}

// Round 10
// 262.900 us; speedup vs baseline: 1.0119x; 1.0119x over previous
//
#include <hip/hip_runtime.h>
#include <hip/hip_bf16.h>
#include <cstdint>

typedef __bf16 bf16;
typedef __bf16 bf16x8 __attribute__((ext_vector_type(8)));
typedef __bf16 bf16x4 __attribute__((ext_vector_type(4)));
typedef float f32x4 __attribute__((ext_vector_type(4)));

__device__ inline bf16x8 cvt8(const float* __restrict__ p) {
  float4 a = *(const float4*)p;
  float4 b = *(const float4*)(p + 4);
  bf16x8 r;
  r[0] = (bf16)a.x; r[1] = (bf16)a.y; r[2] = (bf16)a.z; r[3] = (bf16)a.w;
  r[4] = (bf16)b.x; r[5] = (bf16)b.y; r[6] = (bf16)b.z; r[7] = (bf16)b.w;
  return r;
}

// async global->LDS, 16B per lane; LDS dest = wave-uniform base + lane*16 (m97/m104)
__device__ inline void gl_lds16(const bf16* g, bf16* l) {
  auto gp = reinterpret_cast<const __attribute__((address_space(1))) uint32_t*>(
      reinterpret_cast<uintptr_t>(g));
  auto lp = reinterpret_cast<__attribute__((address_space(3))) uint32_t*>(
      reinterpret_cast<uintptr_t>(l));
  __builtin_amdgcn_global_load_lds(gp, lp, 16, 0, 0);
}

#define BAR() asm volatile("s_barrier" ::: "memory")

// ---------------------------------------------------------------- fused prep
__global__ __launch_bounds__(256) void prep_k(const float* __restrict__ x,
                                              bf16* __restrict__ xb,
                                              const float* __restrict__ wqkv,
                                              bf16* __restrict__ wqkvT,
                                              const float* __restrict__ wo,
                                              bf16* __restrict__ woT) {
  __shared__ bf16 T[32][33];
  const int bid = blockIdx.x;
  if (bid < 4096) {
    long i = ((long)bid * 256 + threadIdx.x) * 8;
    *(bf16x8*)(xb + i) = cvt8(x + i);
    return;
  }
  const float* in;
  bf16* out;
  int R, C, bx, by;
  if (bid < 7168) {
    int t = bid - 4096;
    in = wqkv; out = wqkvT; R = 1024; C = 3072;
    bx = t % 96; by = t / 96;
  } else {
    int t = bid - 7168;
    in = wo; out = woT; R = 1024; C = 1024;
    bx = t % 32; by = t / 32;
  }
  int tc = bx * 32, tr = by * 32;
  int c = threadIdx.x & 31, r8 = threadIdx.x >> 5;
#pragma unroll
  for (int i = 0; i < 4; i++) {
    int r = r8 + i * 8;
    T[r][c] = (bf16)in[(long)(tr + r) * C + tc + c];
  }
  __syncthreads();
#pragma unroll
  for (int i = 0; i < 4; i++) {
    int r = r8 + i * 8;
    out[(long)(tc + r) * R + tr + c] = T[c][r];
  }
}

// ---------------------------------------------------------------- 128x256 QKV GEMM (r6-proven)
// rotated pipeline: MFMA(frags kt) -> vmcnt(0) [STAGE(kt+1) issued one iter ago] ->
// ONE s_barrier -> ds_read frags(kt+1) -> STAGE(kt+2). 48KB LDS, 3 blocks/CU, grid 768.
// q-epilogue folds 8*log2(e) so attn uses exp2 with MFMA C-init bias (no per-elem sub).
__global__ __launch_bounds__(512, 4) void gemm256(const bf16* __restrict__ A,
                                                  const bf16* __restrict__ Bt,
                                                  const float* __restrict__ bias,
                                                  int K,
                                                  bf16* __restrict__ qb,
                                                  bf16* __restrict__ kb,
                                                  bf16* __restrict__ v4,
                                                  const float* __restrict__ qg,
                                                  const float* __restrict__ kg) {
  __shared__ __align__(16) bf16 As[2][4096];  // [buf][128 rows][32 cols] swizzled
  __shared__ __align__(16) bf16 Bs[2][8192];  // [buf][256 rows][32 cols] swizzled

  const int tid = threadIdx.x;
  const int lane = tid & 63;
  const int w = tid >> 6;
  const int quad = lane >> 4;
  const int l16 = lane & 15;
  const int wr = w >> 2;
  const int wc = w & 3;

  // bijective XCD swizzle (nwg = 768, %8 == 0)
  const int gx = gridDim.x;  // 12
  const int bid = blockIdx.y * gx + blockIdx.x;
  const int cpx = (gx * gridDim.y) >> 3;
  const int sw = (bid & 7) * cpx + (bid >> 3);
  const int n0 = (sw % gx) * 256;
  const int m0 = (sw / gx) * 128;

  const int srA = tid >> 2;                         // 0..127
  const int scS = ((tid & 3) ^ ((tid >> 3) & 3)) * 8;
  const bf16* aS = A + (long)(m0 + srA) * K + scS;
  const bf16* bS0 = Bt + (long)(n0 + srA) * K + scS;
  const bf16* bS1 = bS0 + (long)128 * K;

#define STAGE(tb, kt1)                                                   \
  {                                                                      \
    const long kc = (long)(kt1)*32;                                      \
    gl_lds16(aS + kc, &As[tb][w * 512]);                                 \
    gl_lds16(bS0 + kc, &Bs[tb][w * 512]);                                \
    gl_lds16(bS1 + kc, &Bs[tb][4096 + w * 512]);                         \
  }

  const int cphys = (quad ^ ((l16 >> 1) & 3)) * 8;
  const int aoff = (wr * 64 + l16) * 32 + cphys;
  const int boff = (wc * 64 + l16) * 32 + cphys;

#define LOADFRAGS(pb)                                                          \
  {                                                                            \
    _Pragma("unroll") for (int n = 0; n < 4; n++) bfr[n] =                     \
        *(const bf16x8*)&Bs[pb][boff + n * 512];                               \
    _Pragma("unroll") for (int m = 0; m < 4; m++) afr[m] =                     \
        *(const bf16x8*)&As[pb][aoff + m * 512];                               \
  }

  f32x4 acc[4][4];
#pragma unroll
  for (int i = 0; i < 4; i++)
#pragma unroll
    for (int j = 0; j < 4; j++) acc[i][j] = f32x4{0.f, 0.f, 0.f, 0.f};

  const int NK = K >> 5;  // 32
  bf16x8 afr[4], bfr[4];

  STAGE(0, 0);
  asm volatile("s_waitcnt vmcnt(0)" ::: "memory");
  BAR();
  LOADFRAGS(0);
  STAGE(1, 1);

  for (int kt = 0; kt < NK; ++kt) {
    __builtin_amdgcn_s_setprio(1);
#pragma unroll
    for (int m = 0; m < 4; m++)
#pragma unroll
      for (int n = 0; n < 4; n++)
        acc[m][n] = __builtin_amdgcn_mfma_f32_16x16x32_bf16(afr[m], bfr[n], acc[m][n], 0, 0, 0);
    __builtin_amdgcn_s_setprio(0);
    if (kt + 1 < NK) {
      asm volatile("s_waitcnt vmcnt(0)" ::: "memory");
      BAR();
      LOADFRAGS((kt + 1) & 1);
      if (kt + 2 < NK) STAGE(kt & 1, kt + 2);
    }
  }

  // ---------------- epilogue (m89/m91 C layout)
  const int which = n0 >> 10;  // 0=q, 1=k, 2=v
  if (which == 2) {
    const int T0 = (((m0 & 1023) + wr * 64) >> 2) + quad;
    const int bh = (m0 >> 10) * 16 + (((n0 + wc * 64) & 1023) >> 6);
#pragma unroll
    for (int m = 0; m < 4; m++) {
#pragma unroll
      for (int n = 0; n < 4; n++) {
        int ng = n0 + wc * 64 + n * 16 + l16;
        int dc = n * 16 + l16;
        float bj = bias[ng];
        bf16x4 pv;
#pragma unroll
        for (int r = 0; r < 4; r++) pv[r] = (bf16)(acc[m][n][r] + bj);
        *(bf16x4*)(v4 + ((long)bh * 16384 + (long)(T0 + m * 4) * 64 + dc) * 4) = pv;
      }
    }
    return;
  }

  const float* gg = which ? kg : qg;
  bf16* dst = which ? kb : qb;
  // q folds cos-sim scale * log2(e): attn computes p = exp2(st), bias in MFMA C-init
  const float fold = which ? 1.0f : 11.541560327111708f;
  const int h = ((n0 + wc * 64) & 1023) >> 6;
  const int bh = (m0 >> 10) * 16 + h;
  float bj[4], gain[4];
#pragma unroll
  for (int j = 0; j < 4; j++) {
    bj[j] = bias[n0 + wc * 64 + j * 16 + l16];
    gain[j] = gg[j * 16 + l16];
  }
  const float f = exp2f((float)l16 * (-13.287712379549449f / 16.0f));  // 10000^(-l16/16)

#pragma unroll
  for (int m = 0; m < 4; m++) {
#pragma unroll
    for (int r = 0; r < 4; r++) {
      int ntok = (m0 & 1023) + wr * 64 + m * 16 + quad * 4 + r;
      float v0 = acc[m][0][r] + bj[0];
      float v1 = acc[m][1][r] + bj[1];
      float v2 = acc[m][2][r] + bj[2];
      float v3 = acc[m][3][r] + bj[3];
      float ss = v0 * v0 + v1 * v1 + v2 * v2 + v3 * v3;
#pragma unroll
      for (int mk = 1; mk <= 8; mk <<= 1) ss += __shfl_xor(ss, mk, 64);
      float rms = rsqrtf(ss * (1.0f / 64.0f) + 1e-6f);
      v0 *= rms * gain[0]; v1 *= rms * gain[1]; v2 *= rms * gain[2]; v3 *= rms * gain[3];
      float sh, ch_, swv, cw;
      __sincosf((float)(ntok >> 5) * f, &sh, &ch_);
      __sincosf((float)(ntok & 31) * f, &swv, &cw);
      float w0 = v0 * ch_ - v2 * sh;
      float w1 = v1 * cw - v3 * swv;
      float w2 = v2 * ch_ + v0 * sh;
      float w3 = v3 * cw + v1 * swv;
      float nn = w0 * w0 + w1 * w1 + w2 * w2 + w3 * w3;
#pragma unroll
      for (int mk = 1; mk <= 8; mk <<= 1) nn += __shfl_xor(nn, mk, 64);
      float inv = rsqrtf(nn) * fold;
      long base = ((long)bh * 1024 + ntok) * 64 + l16;
      dst[base] = (bf16)(w0 * inv);
      dst[base + 16] = (bf16)(w1 * inv);
      dst[base + 32] = (bf16)(w2 * inv);
      dst[base + 48] = (bf16)(w3 * inv);
    }
  }
}

// ---------------------------------------------------------------- out-proj GEMM 128^2 (r6-proven)
__global__ __launch_bounds__(256, 4) void gemm_bt1(const bf16* __restrict__ A,
                                                   const bf16* __restrict__ Bt,
                                                   const float* __restrict__ bias,
                                                   int N, int K,
                                                   float* __restrict__ out) {
  __shared__ __align__(16) bf16 As[2][4096];  // [buf][128][32] swizzled
  __shared__ __align__(16) bf16 Bs[2][4096];

  const int tid = threadIdx.x;
  const int lane = tid & 63;
  const int w = tid >> 6;
  const int wm = (w & 1) * 64;
  const int wn = (w >> 1) * 64;
  const int quad = lane >> 4;
  const int l16 = lane & 15;

  const int m0 = blockIdx.y * 128;
  const int n0 = blockIdx.x * 128;

  int srow[2], scof[2];
#pragma unroll
  for (int l = 0; l < 2; l++) {
    int s = l * 256 + tid;
    srow[l] = s >> 2;
    scof[l] = ((s & 3) ^ ((s >> 3) & 3)) * 8;
  }

  auto stage = [&](int tb, int k0) {
    int hh = k0 >> 6;
#pragma unroll
    for (int l = 0; l < 2; l++) {
      int m1 = m0 + srow[l];
      int dc = (k0 & 63) + scof[l];
      const bf16* ga = A + ((long)((m1 >> 10) * 16 + hh) * 1024 + (m1 & 1023)) * 64 + dc;
      gl_lds16(ga, &As[tb][l * 2048 + w * 512]);
      gl_lds16(Bt + (long)(n0 + srow[l]) * K + k0 + scof[l], &Bs[tb][l * 2048 + w * 512]);
    }
  };

  const int cphys = (quad ^ ((l16 >> 1) & 3)) * 8;

  f32x4 acc[4][4];
#pragma unroll
  for (int i = 0; i < 4; i++)
#pragma unroll
    for (int j = 0; j < 4; j++) acc[i][j] = f32x4{0.f, 0.f, 0.f, 0.f};

  const int NK = K >> 5;  // 32
  bf16x8 af[4], bfr[4];

#define LOADFRAGS1(pb)                                                         \
  {                                                                            \
    _Pragma("unroll") for (int i = 0; i < 4; i++) {                            \
      af[i] = *(const bf16x8*)&As[pb][(wm + i * 16 + l16) * 32 + cphys];       \
      bfr[i] = *(const bf16x8*)&Bs[pb][(wn + i * 16 + l16) * 32 + cphys];      \
    }                                                                          \
  }

  stage(0, 0);
  asm volatile("s_waitcnt vmcnt(0)" ::: "memory");
  BAR();
  LOADFRAGS1(0);
  stage(1, 32);

  for (int kt = 0; kt < NK; ++kt) {
    __builtin_amdgcn_s_setprio(1);
#pragma unroll
    for (int i = 0; i < 4; i++)
#pragma unroll
      for (int j = 0; j < 4; j++)
        acc[i][j] = __builtin_amdgcn_mfma_f32_16x16x32_bf16(af[i], bfr[j], acc[i][j], 0, 0, 0);
    __builtin_amdgcn_s_setprio(0);
    if (kt + 1 < NK) {
      asm volatile("s_waitcnt vmcnt(0)" ::: "memory");
      BAR();
      LOADFRAGS1((kt + 1) & 1);
      if (kt + 2 < NK) stage(kt & 1, (kt + 2) << 5);
    }
  }

#pragma unroll
  for (int i = 0; i < 4; i++)
#pragma unroll
    for (int j = 0; j < 4; j++)
#pragma unroll
      for (int r = 0; r < 4; r++) {
        int mg = m0 + wm + i * 16 + quad * 4 + r;
        int ng = n0 + wn + j * 16 + l16;
        out[(long)mg * N + ng] = acc[i][j][r] + bias[ng];
      }
}

// ---------------------------------------------------------------- flash attention
// r10: REVERT to the r6-proven 4-wave structure (242.7us config; attn <73us there),
// grid (4,128), 256 threads, 2 blocks/CU. Kept from r9 only the mechanically-proven
// VALU cuts (measured: VALU cycles 37.7 -> 33.2): softmax bias in MFMA C-init,
// p = exp2(st) [scale*log2e folded into q by gemm256], f32x4 parallel denominator.
// r8/r9's 2-wave + co-location restructures are abandoned (added stall, net loss).
__global__ __launch_bounds__(256, 2) void attn_k(bf16* __restrict__ qb,
                                                 const bf16* __restrict__ kb,
                                                 const bf16* __restrict__ v4) {
  __shared__ __align__(16) bf16 Ks[2][64][72];     // keys x d (padded, dbuf)
  __shared__ __align__(16) bf16 Vl[2][4096];       // linear v4 tile (dbuf)
  __shared__ __align__(16) bf16 Ps[4][2][16][72];  // per-wave P, 2 pipeline slots

  const int tid = threadIdx.x;
  const int lane = tid & 63;
  const int w = tid >> 6;
  const int quad = lane >> 4;
  const int l16 = lane & 15;

  const int bh = blockIdx.y;
  const int q0 = blockIdx.x * 256 + w * 64;

  const f32x4 NEGB = f32x4{-11.541560327111708f, -11.541560327111708f,
                           -11.541560327111708f, -11.541560327111708f};

  // Q fragments for 4 query groups (q already holds cos-sim scale * log2e)
  bf16x8 aq[4][2];
  long qrow[4];
#pragma unroll
  for (int g = 0; g < 4; g++) {
    qrow[g] = ((long)bh * 1024 + q0 + g * 16 + l16) * 64;
    aq[g][0] = *(const bf16x8*)(qb + qrow[g] + quad * 8);
    aq[g][1] = *(const bf16x8*)(qb + qrow[g] + 32 + quad * 8);
  }

  f32x4 o[4][4];
#pragma unroll
  for (int g = 0; g < 4; g++)
#pragma unroll
    for (int i = 0; i < 4; i++) o[g][i] = f32x4{0.f, 0.f, 0.f, 0.f};
  f32x4 lsv[4];
#pragma unroll
  for (int g = 0; g < 4; g++) lsv[g] = f32x4{0.f, 0.f, 0.f, 0.f};

  const int sr = tid >> 3, sc = (tid & 7) * 8;  // K staging: 32 rows x 64 cols per load
  const bf16* kbase = kb + (long)bh * 65536;
  const bf16* vbase = v4 + (long)bh * 65536;

  // prologue: stage tile 0 into buffer 0
  bf16x8 kr0 = *(const bf16x8*)(kbase + (long)sr * 64 + sc);
  bf16x8 kr1 = *(const bf16x8*)(kbase + (long)(sr + 32) * 64 + sc);
  gl_lds16(vbase + (w * 2) * 512 + lane * 8, &Vl[0][(w * 2) * 512]);
  gl_lds16(vbase + (w * 2 + 1) * 512 + lane * 8, &Vl[0][(w * 2 + 1) * 512]);
  asm volatile("s_waitcnt vmcnt(0)" ::: "memory");
  *(bf16x8*)&Ks[0][sr][sc] = kr0;
  *(bf16x8*)&Ks[0][sr + 32][sc] = kr1;
  asm volatile("s_waitcnt lgkmcnt(0)" ::: "memory");
  BAR();

  for (int kt = 0; kt < 1024; kt += 64) {
    const int cur = (kt >> 6) & 1;
    const bool pf = (kt + 64 < 1024);
    // issue next tile's staging loads (K -> regs, V -> alternate LDS buffer)
    if (pf) {
      kr0 = *(const bf16x8*)(kbase + (long)(kt + 64 + sr) * 64 + sc);
      kr1 = *(const bf16x8*)(kbase + (long)(kt + 64 + sr + 32) * 64 + sc);
      gl_lds16(vbase + (long)(kt + 64) * 64 + (w * 2) * 512 + lane * 8,
               &Vl[cur ^ 1][(w * 2) * 512]);
      gl_lds16(vbase + (long)(kt + 64) * 64 + (w * 2 + 1) * 512 + lane * 8,
               &Vl[cur ^ 1][(w * 2 + 1) * 512]);
    }

    // hoist K-frags and V-frags for this tile
    bf16x8 kf[4][2], vf[4][2];
#pragma unroll
    for (int i = 0; i < 4; i++) {
      kf[i][0] = *(const bf16x8*)&Ks[cur][i * 16 + l16][quad * 8];
      kf[i][1] = *(const bf16x8*)&Ks[cur][i * 16 + l16][32 + quad * 8];
      int D4 = (i * 16 + l16) * 4;
      bf16x4 a0 = *(const bf16x4*)&Vl[cur][quad * 512 + D4];
      bf16x4 a1 = *(const bf16x4*)&Vl[cur][quad * 512 + D4 + 256];
      bf16x4 a2 = *(const bf16x4*)&Vl[cur][quad * 512 + D4 + 2048];
      bf16x4 a3 = *(const bf16x4*)&Vl[cur][quad * 512 + D4 + 2048 + 256];
      vf[i][0] = __builtin_shufflevector(a0, a1, 0, 1, 2, 3, 4, 5, 6, 7);
      vf[i][1] = __builtin_shufflevector(a2, a3, 0, 1, 2, 3, 4, 5, 6, 7);
    }

    bf16x8 bp[2][2];
#pragma unroll
    for (int g = 0; g < 4; g++) {
      const int sl = g & 1;
      // St = K_tile · Qg^T + (-8*log2e) [C-init]; p = exp2(st); lsv: 4 parallel chains
#pragma unroll
      for (int i = 0; i < 4; i++) {
        f32x4 st = __builtin_amdgcn_mfma_f32_16x16x32_bf16(kf[i][0], aq[g][0], NEGB, 0, 0, 0);
        st = __builtin_amdgcn_mfma_f32_16x16x32_bf16(kf[i][1], aq[g][1], st, 0, 0, 0);
        bf16x4 pk;
#pragma unroll
        for (int r = 0; r < 4; r++) {
          float p = exp2f(st[r]);
          lsv[g][r] += p;
          pk[r] = (bf16)p;
        }
        *(bf16x4*)&Ps[w][sl][l16][i * 16 + quad * 4] = pk;
      }
      // issue this group's P reads immediately (same-wave DS in-order: RAW safe);
      // consumed one group later under the next QK's MFMAs.
      bp[sl][0] = *(const bf16x8*)&Ps[w][sl][l16][quad * 8];
      bp[sl][1] = *(const bf16x8*)&Ps[w][sl][l16][32 + quad * 8];
      if (g > 0) {
        const int pg = (g - 1) & 1;
#pragma unroll
        for (int i = 0; i < 4; i++) {
          o[g - 1][i] = __builtin_amdgcn_mfma_f32_16x16x32_bf16(vf[i][0], bp[pg][0], o[g - 1][i], 0, 0, 0);
          o[g - 1][i] = __builtin_amdgcn_mfma_f32_16x16x32_bf16(vf[i][1], bp[pg][1], o[g - 1][i], 0, 0, 0);
        }
      }
    }
    // pipeline drain: PV for group 3
#pragma unroll
    for (int i = 0; i < 4; i++) {
      o[3][i] = __builtin_amdgcn_mfma_f32_16x16x32_bf16(vf[i][0], bp[1][0], o[3][i], 0, 0, 0);
      o[3][i] = __builtin_amdgcn_mfma_f32_16x16x32_bf16(vf[i][1], bp[1][1], o[3][i], 0, 0, 0);
    }

    // commit next tile: wait K regs + V gl_lds (covered by the g-loop), write K to LDS
    if (pf) {
      asm volatile("s_waitcnt vmcnt(0)" ::: "memory");
      *(bf16x8*)&Ks[cur ^ 1][sr][sc] = kr0;
      *(bf16x8*)&Ks[cur ^ 1][sr + 32][sc] = kr1;
    }
    asm volatile("s_waitcnt lgkmcnt(0)" ::: "memory");
    BAR();
  }

#pragma unroll
  for (int g = 0; g < 4; g++) {
    float l = (lsv[g][0] + lsv[g][1]) + (lsv[g][2] + lsv[g][3]);
    l += __shfl_xor(l, 16, 64);
    l += __shfl_xor(l, 32, 64);
    float inv = 1.0f / l;
#pragma unroll
    for (int i = 0; i < 4; i++) {
      bf16x4 ov;
#pragma unroll
      for (int r = 0; r < 4; r++) ov[r] = (bf16)(o[g][i][r] * inv);
      *(bf16x4*)(qb + qrow[g] + i * 16 + quad * 4) = ov;
    }
  }
}

// ---------------------------------------------------------------- launcher
extern "C" void kernel_launch(void* const* d_in, const int* in_sizes, int n_in,
                              void* d_out, int out_size, void* d_ws, size_t ws_size,
                              hipStream_t stream) {
  (void)in_sizes; (void)n_in; (void)out_size; (void)ws_size;
  const float* x     = (const float*)d_in[0];
  const float* w_qkv = (const float*)d_in[1];
  const float* b_qkv = (const float*)d_in[2];
  const float* q_g   = (const float*)d_in[3];
  const float* k_g   = (const float*)d_in[4];
  const float* w_out = (const float*)d_in[5];
  const float* b_out = (const float*)d_in[6];
  float* out = (float*)d_out;

  char* ws = (char*)d_ws;
  bf16* wqkvT = (bf16*)ws; ws += (long)3072 * 1024 * 2;      // 6 MB
  bf16* woT   = (bf16*)ws; ws += (long)1024 * 1024 * 2;      // 2 MB
  bf16* xb    = (bf16*)ws; ws += (long)8192 * 1024 * 2;      // 16 MB
  bf16* qb    = (bf16*)ws; ws += (long)128 * 1024 * 64 * 2;  // 16 MB (q, then attention O)
  bf16* kb    = (bf16*)ws; ws += (long)128 * 1024 * 64 * 2;  // 16 MB
  bf16* v4    = (bf16*)ws; ws += (long)128 * 64 * 1024 * 2;  // 16 MB   (total 72 MB)

  prep_k<<<8192, 256, 0, stream>>>(x, xb, w_qkv, wqkvT, w_out, woT);
  gemm256<<<dim3(3072 / 256, 8192 / 128), 512, 0, stream>>>(xb, wqkvT, b_qkv, 1024,
                                                            qb, kb, v4, q_g, k_g);
  attn_k<<<dim3(4, 128), 256, 0, stream>>>(qb, kb, v4);
  gemm_bt1<<<dim3(1024 / 128, 8192 / 128), 256, 0, stream>>>(qb, woT, b_out,
                                                             1024, 1024, out);
}

// Round 11
// 240.729 us; speedup vs baseline: 1.1051x; 1.0921x over previous
//
#include <hip/hip_runtime.h>
#include <hip/hip_bf16.h>
#include <cstdint>

typedef __bf16 bf16;
typedef __bf16 bf16x8 __attribute__((ext_vector_type(8)));
typedef __bf16 bf16x4 __attribute__((ext_vector_type(4)));
typedef float f32x4 __attribute__((ext_vector_type(4)));

__device__ inline bf16x8 cvt8(const float* __restrict__ p) {
  float4 a = *(const float4*)p;
  float4 b = *(const float4*)(p + 4);
  bf16x8 r;
  r[0] = (bf16)a.x; r[1] = (bf16)a.y; r[2] = (bf16)a.z; r[3] = (bf16)a.w;
  r[4] = (bf16)b.x; r[5] = (bf16)b.y; r[6] = (bf16)b.z; r[7] = (bf16)b.w;
  return r;
}

// async global->LDS, 16B per lane; LDS dest = wave-uniform base + lane*16 (m97/m104)
__device__ inline void gl_lds16(const bf16* g, bf16* l) {
  auto gp = reinterpret_cast<const __attribute__((address_space(1))) uint32_t*>(
      reinterpret_cast<uintptr_t>(g));
  auto lp = reinterpret_cast<__attribute__((address_space(3))) uint32_t*>(
      reinterpret_cast<uintptr_t>(l));
  __builtin_amdgcn_global_load_lds(gp, lp, 16, 0, 0);
}

#define BAR() asm volatile("s_barrier" ::: "memory")

// ---------------------------------------------------------------- fused prep
__global__ __launch_bounds__(256) void prep_k(const float* __restrict__ x,
                                              bf16* __restrict__ xb,
                                              const float* __restrict__ wqkv,
                                              bf16* __restrict__ wqkvT,
                                              const float* __restrict__ wo,
                                              bf16* __restrict__ woT) {
  __shared__ bf16 T[32][33];
  const int bid = blockIdx.x;
  if (bid < 4096) {
    long i = ((long)bid * 256 + threadIdx.x) * 8;
    *(bf16x8*)(xb + i) = cvt8(x + i);
    return;
  }
  const float* in;
  bf16* out;
  int R, C, bx, by;
  if (bid < 7168) {
    int t = bid - 4096;
    in = wqkv; out = wqkvT; R = 1024; C = 3072;
    bx = t % 96; by = t / 96;
  } else {
    int t = bid - 7168;
    in = wo; out = woT; R = 1024; C = 1024;
    bx = t % 32; by = t / 32;
  }
  int tc = bx * 32, tr = by * 32;
  int c = threadIdx.x & 31, r8 = threadIdx.x >> 5;
#pragma unroll
  for (int i = 0; i < 4; i++) {
    int r = r8 + i * 8;
    T[r][c] = (bf16)in[(long)(tr + r) * C + tc + c];
  }
  __syncthreads();
#pragma unroll
  for (int i = 0; i < 4; i++) {
    int r = r8 + i * 8;
    out[(long)(tc + r) * R + tr + c] = T[c][r];
  }
}

// ---------------------------------------------------------------- 128x256 QKV GEMM (r6-proven BEST: 73.4us)
// rotated pipeline: MFMA(frags kt) -> vmcnt(0) [STAGE(kt+1) issued one iter ago] ->
// ONE raw s_barrier -> ds_read frags(kt+1) -> STAGE(kt+2). 48KB LDS, 3 blocks/CU,
// grid 768 = 3/CU exact. XOR swizzle via pre-swizzled global source (conflicts = 0).
// q/k epilogue: bias+RMSNorm+RoPE+l2, q folds cos-sim scale 8 (attn uses __expf(st-8)).
__global__ __launch_bounds__(512, 4) void gemm256(const bf16* __restrict__ A,
                                                  const bf16* __restrict__ Bt,
                                                  const float* __restrict__ bias,
                                                  int K,
                                                  bf16* __restrict__ qb,
                                                  bf16* __restrict__ kb,
                                                  bf16* __restrict__ v4,
                                                  const float* __restrict__ qg,
                                                  const float* __restrict__ kg) {
  __shared__ __align__(16) bf16 As[2][4096];  // [buf][128 rows][32 cols] swizzled
  __shared__ __align__(16) bf16 Bs[2][8192];  // [buf][256 rows][32 cols] swizzled

  const int tid = threadIdx.x;
  const int lane = tid & 63;
  const int w = tid >> 6;
  const int quad = lane >> 4;
  const int l16 = lane & 15;
  const int wr = w >> 2;
  const int wc = w & 3;

  // bijective XCD swizzle (nwg = 768, %8 == 0)
  const int gx = gridDim.x;  // 12
  const int bid = blockIdx.y * gx + blockIdx.x;
  const int cpx = (gx * gridDim.y) >> 3;
  const int sw = (bid & 7) * cpx + (bid >> 3);
  const int n0 = (sw % gx) * 256;
  const int m0 = (sw / gx) * 128;

  const int srA = tid >> 2;                         // 0..127
  const int scS = ((tid & 3) ^ ((tid >> 3) & 3)) * 8;
  const bf16* aS = A + (long)(m0 + srA) * K + scS;
  const bf16* bS0 = Bt + (long)(n0 + srA) * K + scS;
  const bf16* bS1 = bS0 + (long)128 * K;

#define STAGE(tb, kt1)                                                   \
  {                                                                      \
    const long kc = (long)(kt1)*32;                                      \
    gl_lds16(aS + kc, &As[tb][w * 512]);                                 \
    gl_lds16(bS0 + kc, &Bs[tb][w * 512]);                                \
    gl_lds16(bS1 + kc, &Bs[tb][4096 + w * 512]);                         \
  }

  const int cphys = (quad ^ ((l16 >> 1) & 3)) * 8;
  const int aoff = (wr * 64 + l16) * 32 + cphys;
  const int boff = (wc * 64 + l16) * 32 + cphys;

#define LOADFRAGS(pb)                                                          \
  {                                                                            \
    _Pragma("unroll") for (int n = 0; n < 4; n++) bfr[n] =                     \
        *(const bf16x8*)&Bs[pb][boff + n * 512];                               \
    _Pragma("unroll") for (int m = 0; m < 4; m++) afr[m] =                     \
        *(const bf16x8*)&As[pb][aoff + m * 512];                               \
  }

  f32x4 acc[4][4];
#pragma unroll
  for (int i = 0; i < 4; i++)
#pragma unroll
    for (int j = 0; j < 4; j++) acc[i][j] = f32x4{0.f, 0.f, 0.f, 0.f};

  const int NK = K >> 5;  // 32
  bf16x8 afr[4], bfr[4];

  // prologue: stage tile0 -> b0, read its frags, stage tile1 -> b1
  STAGE(0, 0);
  asm volatile("s_waitcnt vmcnt(0)" ::: "memory");
  BAR();
  LOADFRAGS(0);
  STAGE(1, 1);

  for (int kt = 0; kt < NK; ++kt) {
    __builtin_amdgcn_s_setprio(1);
#pragma unroll
    for (int m = 0; m < 4; m++)
#pragma unroll
      for (int n = 0; n < 4; n++)
        acc[m][n] = __builtin_amdgcn_mfma_f32_16x16x32_bf16(afr[m], bfr[n], acc[m][n], 0, 0, 0);
    __builtin_amdgcn_s_setprio(0);
    if (kt + 1 < NK) {
      asm volatile("s_waitcnt vmcnt(0)" ::: "memory");  // STAGE(kt+1) landed (1 iter of cover)
      BAR();  // every wave past MFMA(kt) => its reads of buf[kt&1] are complete
      LOADFRAGS((kt + 1) & 1);
      if (kt + 2 < NK) STAGE(kt & 1, kt + 2);  // refill the buffer MFMA(kt) freed
    }
  }

  // ---------------- epilogue (m89/m91 C layout)
  const int which = n0 >> 10;  // 0=q, 1=k, 2=v
  if (which == 2) {
    const int T0 = (((m0 & 1023) + wr * 64) >> 2) + quad;
    const int bh = (m0 >> 10) * 16 + (((n0 + wc * 64) & 1023) >> 6);
#pragma unroll
    for (int m = 0; m < 4; m++) {
#pragma unroll
      for (int n = 0; n < 4; n++) {
        int ng = n0 + wc * 64 + n * 16 + l16;
        int dc = n * 16 + l16;
        float bj = bias[ng];
        bf16x4 pv;
#pragma unroll
        for (int r = 0; r < 4; r++) pv[r] = (bf16)(acc[m][n][r] + bj);
        *(bf16x4*)(v4 + ((long)bh * 16384 + (long)(T0 + m * 4) * 64 + dc) * 4) = pv;
      }
    }
    return;
  }

  const float* gg = which ? kg : qg;
  bf16* dst = which ? kb : qb;
  const float fold = which ? 1.0f : 8.0f;
  const int h = ((n0 + wc * 64) & 1023) >> 6;
  const int bh = (m0 >> 10) * 16 + h;
  float bj[4], gain[4];
#pragma unroll
  for (int j = 0; j < 4; j++) {
    bj[j] = bias[n0 + wc * 64 + j * 16 + l16];
    gain[j] = gg[j * 16 + l16];
  }
  const float f = exp2f((float)l16 * (-13.287712379549449f / 16.0f));  // 10000^(-l16/16)

#pragma unroll
  for (int m = 0; m < 4; m++) {
#pragma unroll
    for (int r = 0; r < 4; r++) {
      int ntok = (m0 & 1023) + wr * 64 + m * 16 + quad * 4 + r;
      float v0 = acc[m][0][r] + bj[0];
      float v1 = acc[m][1][r] + bj[1];
      float v2 = acc[m][2][r] + bj[2];
      float v3 = acc[m][3][r] + bj[3];
      float ss = v0 * v0 + v1 * v1 + v2 * v2 + v3 * v3;
#pragma unroll
      for (int mk = 1; mk <= 8; mk <<= 1) ss += __shfl_xor(ss, mk, 64);
      float rms = rsqrtf(ss * (1.0f / 64.0f) + 1e-6f);
      v0 *= rms * gain[0]; v1 *= rms * gain[1]; v2 *= rms * gain[2]; v3 *= rms * gain[3];
      float sh, ch_, swv, cw;
      __sincosf((float)(ntok >> 5) * f, &sh, &ch_);
      __sincosf((float)(ntok & 31) * f, &swv, &cw);
      float w0 = v0 * ch_ - v2 * sh;
      float w1 = v1 * cw - v3 * swv;
      float w2 = v2 * ch_ + v0 * sh;
      float w3 = v3 * cw + v1 * swv;
      float nn = w0 * w0 + w1 * w1 + w2 * w2 + w3 * w3;
#pragma unroll
      for (int mk = 1; mk <= 8; mk <<= 1) nn += __shfl_xor(nn, mk, 64);
      float inv = rsqrtf(nn) * fold;
      long base = ((long)bh * 1024 + ntok) * 64 + l16;
      dst[base] = (bf16)(w0 * inv);
      dst[base + 16] = (bf16)(w1 * inv);
      dst[base + 32] = (bf16)(w2 * inv);
      dst[base + 48] = (bf16)(w3 * inv);
    }
  }
}

// ---------------------------------------------------------------- out-proj GEMM 128^2 (r6-proven)
// same rotated pipeline as gemm256 (MFMA -> vmcnt(0) -> BAR -> reads -> stage).
__global__ __launch_bounds__(256, 4) void gemm_bt1(const bf16* __restrict__ A,
                                                   const bf16* __restrict__ Bt,
                                                   const float* __restrict__ bias,
                                                   int N, int K,
                                                   float* __restrict__ out) {
  __shared__ __align__(16) bf16 As[2][4096];  // [buf][128][32] swizzled
  __shared__ __align__(16) bf16 Bs[2][4096];

  const int tid = threadIdx.x;
  const int lane = tid & 63;
  const int w = tid >> 6;
  const int wm = (w & 1) * 64;
  const int wn = (w >> 1) * 64;
  const int quad = lane >> 4;
  const int l16 = lane & 15;

  const int m0 = blockIdx.y * 128;
  const int n0 = blockIdx.x * 128;

  int srow[2], scof[2];
#pragma unroll
  for (int l = 0; l < 2; l++) {
    int s = l * 256 + tid;
    srow[l] = s >> 2;
    scof[l] = ((s & 3) ^ ((s >> 3) & 3)) * 8;
  }

  auto stage = [&](int tb, int k0) {
    int hh = k0 >> 6;
#pragma unroll
    for (int l = 0; l < 2; l++) {
      int m1 = m0 + srow[l];
      int dc = (k0 & 63) + scof[l];
      const bf16* ga = A + ((long)((m1 >> 10) * 16 + hh) * 1024 + (m1 & 1023)) * 64 + dc;
      gl_lds16(ga, &As[tb][l * 2048 + w * 512]);
      gl_lds16(Bt + (long)(n0 + srow[l]) * K + k0 + scof[l], &Bs[tb][l * 2048 + w * 512]);
    }
  };

  const int cphys = (quad ^ ((l16 >> 1) & 3)) * 8;

  f32x4 acc[4][4];
#pragma unroll
  for (int i = 0; i < 4; i++)
#pragma unroll
    for (int j = 0; j < 4; j++) acc[i][j] = f32x4{0.f, 0.f, 0.f, 0.f};

  const int NK = K >> 5;  // 32
  bf16x8 af[4], bfr[4];

#define LOADFRAGS1(pb)                                                         \
  {                                                                            \
    _Pragma("unroll") for (int i = 0; i < 4; i++) {                            \
      af[i] = *(const bf16x8*)&As[pb][(wm + i * 16 + l16) * 32 + cphys];       \
      bfr[i] = *(const bf16x8*)&Bs[pb][(wn + i * 16 + l16) * 32 + cphys];      \
    }                                                                          \
  }

  stage(0, 0);
  asm volatile("s_waitcnt vmcnt(0)" ::: "memory");
  BAR();
  LOADFRAGS1(0);
  stage(1, 32);

  for (int kt = 0; kt < NK; ++kt) {
    __builtin_amdgcn_s_setprio(1);
#pragma unroll
    for (int i = 0; i < 4; i++)
#pragma unroll
      for (int j = 0; j < 4; j++)
        acc[i][j] = __builtin_amdgcn_mfma_f32_16x16x32_bf16(af[i], bfr[j], acc[i][j], 0, 0, 0);
    __builtin_amdgcn_s_setprio(0);
    if (kt + 1 < NK) {
      asm volatile("s_waitcnt vmcnt(0)" ::: "memory");
      BAR();
      LOADFRAGS1((kt + 1) & 1);
      if (kt + 2 < NK) stage(kt & 1, (kt + 2) << 5);
    }
  }

#pragma unroll
  for (int i = 0; i < 4; i++)
#pragma unroll
    for (int j = 0; j < 4; j++)
#pragma unroll
      for (int r = 0; r < 4; r++) {
        int mg = m0 + wm + i * 16 + quad * 4 + r;
        int ng = n0 + wn + j * 16 + l16;
        out[(long)mg * N + ng] = acc[i][j][r] + bias[ng];
      }
}

// ---------------------------------------------------------------- flash attention (r6-verbatim BEST)
// 4-wave blocks, grid (4,128), 2 blocks/CU. P software-pipelined through LDS across
// groups (same-wave DS in-order; reads issued after stores, consumed one group later).
// K/V staging double-buffered with raw barriers. __expf(st-8), serial ls (verbatim —
// the r8-r10 exp2/NEGB/lsv bundle measured as a 12-16% regression and is abandoned).
__global__ __launch_bounds__(256, 2) void attn_k(bf16* __restrict__ qb,
                                                 const bf16* __restrict__ kb,
                                                 const bf16* __restrict__ v4) {
  __shared__ __align__(16) bf16 Ks[2][64][72];     // keys x d (padded, dbuf)
  __shared__ __align__(16) bf16 Vl[2][4096];       // linear v4 tile (dbuf)
  __shared__ __align__(16) bf16 Ps[4][2][16][72];  // per-wave P, 2 pipeline slots

  const int tid = threadIdx.x;
  const int lane = tid & 63;
  const int w = tid >> 6;
  const int quad = lane >> 4;
  const int l16 = lane & 15;

  const int bh = blockIdx.y;
  const int q0 = blockIdx.x * 256 + w * 64;

  bf16x8 aq[4][2];
  long qrow[4];
#pragma unroll
  for (int g = 0; g < 4; g++) {
    qrow[g] = ((long)bh * 1024 + q0 + g * 16 + l16) * 64;
    aq[g][0] = *(const bf16x8*)(qb + qrow[g] + quad * 8);
    aq[g][1] = *(const bf16x8*)(qb + qrow[g] + 32 + quad * 8);
  }

  f32x4 o[4][4];
#pragma unroll
  for (int g = 0; g < 4; g++)
#pragma unroll
    for (int i = 0; i < 4; i++) o[g][i] = f32x4{0.f, 0.f, 0.f, 0.f};
  float ls[4] = {0.f, 0.f, 0.f, 0.f};

  const int sr = tid >> 3, sc = (tid & 7) * 8;
  const bf16* kbase = kb + (long)bh * 65536;
  const bf16* vbase = v4 + (long)bh * 65536;

  bf16x8 kr0 = *(const bf16x8*)(kbase + (long)sr * 64 + sc);
  bf16x8 kr1 = *(const bf16x8*)(kbase + (long)(sr + 32) * 64 + sc);
  gl_lds16(vbase + (w * 2) * 512 + lane * 8, &Vl[0][(w * 2) * 512]);
  gl_lds16(vbase + (w * 2 + 1) * 512 + lane * 8, &Vl[0][(w * 2 + 1) * 512]);
  asm volatile("s_waitcnt vmcnt(0)" ::: "memory");
  *(bf16x8*)&Ks[0][sr][sc] = kr0;
  *(bf16x8*)&Ks[0][sr + 32][sc] = kr1;
  asm volatile("s_waitcnt lgkmcnt(0)" ::: "memory");
  BAR();

  for (int kt = 0; kt < 1024; kt += 64) {
    const int cur = (kt >> 6) & 1;
    const bool pf = (kt + 64 < 1024);
    if (pf) {
      kr0 = *(const bf16x8*)(kbase + (long)(kt + 64 + sr) * 64 + sc);
      kr1 = *(const bf16x8*)(kbase + (long)(kt + 64 + sr + 32) * 64 + sc);
      gl_lds16(vbase + (long)(kt + 64) * 64 + (w * 2) * 512 + lane * 8,
               &Vl[cur ^ 1][(w * 2) * 512]);
      gl_lds16(vbase + (long)(kt + 64) * 64 + (w * 2 + 1) * 512 + lane * 8,
               &Vl[cur ^ 1][(w * 2 + 1) * 512]);
    }

    bf16x8 kf[4][2], vf[4][2];
#pragma unroll
    for (int i = 0; i < 4; i++) {
      kf[i][0] = *(const bf16x8*)&Ks[cur][i * 16 + l16][quad * 8];
      kf[i][1] = *(const bf16x8*)&Ks[cur][i * 16 + l16][32 + quad * 8];
      int D4 = (i * 16 + l16) * 4;
      bf16x4 a0 = *(const bf16x4*)&Vl[cur][quad * 512 + D4];
      bf16x4 a1 = *(const bf16x4*)&Vl[cur][quad * 512 + D4 + 256];
      bf16x4 a2 = *(const bf16x4*)&Vl[cur][quad * 512 + D4 + 2048];
      bf16x4 a3 = *(const bf16x4*)&Vl[cur][quad * 512 + D4 + 2048 + 256];
      vf[i][0] = __builtin_shufflevector(a0, a1, 0, 1, 2, 3, 4, 5, 6, 7);
      vf[i][1] = __builtin_shufflevector(a2, a3, 0, 1, 2, 3, 4, 5, 6, 7);
    }

    bf16x8 bp[2][2];
#pragma unroll
    for (int g = 0; g < 4; g++) {
      const int sl = g & 1;
#pragma unroll
      for (int i = 0; i < 4; i++) {
        f32x4 st = f32x4{0.f, 0.f, 0.f, 0.f};
        st = __builtin_amdgcn_mfma_f32_16x16x32_bf16(kf[i][0], aq[g][0], st, 0, 0, 0);
        st = __builtin_amdgcn_mfma_f32_16x16x32_bf16(kf[i][1], aq[g][1], st, 0, 0, 0);
        bf16x4 pk;
#pragma unroll
        for (int r = 0; r < 4; r++) {
          float p = __expf(st[r] - 8.0f);
          ls[g] += p;
          pk[r] = (bf16)p;
        }
        *(bf16x4*)&Ps[w][sl][l16][i * 16 + quad * 4] = pk;
      }
      bp[sl][0] = *(const bf16x8*)&Ps[w][sl][l16][quad * 8];
      bp[sl][1] = *(const bf16x8*)&Ps[w][sl][l16][32 + quad * 8];
      if (g > 0) {
        const int pg = (g - 1) & 1;
#pragma unroll
        for (int i = 0; i < 4; i++) {
          o[g - 1][i] = __builtin_amdgcn_mfma_f32_16x16x32_bf16(vf[i][0], bp[pg][0], o[g - 1][i], 0, 0, 0);
          o[g - 1][i] = __builtin_amdgcn_mfma_f32_16x16x32_bf16(vf[i][1], bp[pg][1], o[g - 1][i], 0, 0, 0);
        }
      }
    }
#pragma unroll
    for (int i = 0; i < 4; i++) {
      o[3][i] = __builtin_amdgcn_mfma_f32_16x16x32_bf16(vf[i][0], bp[1][0], o[3][i], 0, 0, 0);
      o[3][i] = __builtin_amdgcn_mfma_f32_16x16x32_bf16(vf[i][1], bp[1][1], o[3][i], 0, 0, 0);
    }

    if (pf) {
      asm volatile("s_waitcnt vmcnt(0)" ::: "memory");
      *(bf16x8*)&Ks[cur ^ 1][sr][sc] = kr0;
      *(bf16x8*)&Ks[cur ^ 1][sr + 32][sc] = kr1;
    }
    asm volatile("s_waitcnt lgkmcnt(0)" ::: "memory");
    BAR();
  }

#pragma unroll
  for (int g = 0; g < 4; g++) {
    float l = ls[g];
    l += __shfl_xor(l, 16, 64);
    l += __shfl_xor(l, 32, 64);
    float inv = 1.0f / l;
#pragma unroll
    for (int i = 0; i < 4; i++) {
      bf16x4 ov;
#pragma unroll
      for (int r = 0; r < 4; r++) ov[r] = (bf16)(o[g][i][r] * inv);
      *(bf16x4*)(qb + qrow[g] + i * 16 + quad * 4) = ov;
    }
  }
}

// ---------------------------------------------------------------- launcher
extern "C" void kernel_launch(void* const* d_in, const int* in_sizes, int n_in,
                              void* d_out, int out_size, void* d_ws, size_t ws_size,
                              hipStream_t stream) {
  (void)in_sizes; (void)n_in; (void)out_size; (void)ws_size;
  const float* x     = (const float*)d_in[0];
  const float* w_qkv = (const float*)d_in[1];
  const float* b_qkv = (const float*)d_in[2];
  const float* q_g   = (const float*)d_in[3];
  const float* k_g   = (const float*)d_in[4];
  const float* w_out = (const float*)d_in[5];
  const float* b_out = (const float*)d_in[6];
  float* out = (float*)d_out;

  char* ws = (char*)d_ws;
  bf16* wqkvT = (bf16*)ws; ws += (long)3072 * 1024 * 2;      // 6 MB
  bf16* woT   = (bf16*)ws; ws += (long)1024 * 1024 * 2;      // 2 MB
  bf16* xb    = (bf16*)ws; ws += (long)8192 * 1024 * 2;      // 16 MB
  bf16* qb    = (bf16*)ws; ws += (long)128 * 1024 * 64 * 2;  // 16 MB (q, then attention O)
  bf16* kb    = (bf16*)ws; ws += (long)128 * 1024 * 64 * 2;  // 16 MB
  bf16* v4    = (bf16*)ws; ws += (long)128 * 64 * 1024 * 2;  // 16 MB   (total 72 MB)

  prep_k<<<8192, 256, 0, stream>>>(x, xb, w_qkv, wqkvT, w_out, woT);
  gemm256<<<dim3(3072 / 256, 8192 / 128), 512, 0, stream>>>(xb, wqkvT, b_qkv, 1024,
                                                            qb, kb, v4, q_g, k_g);
  attn_k<<<dim3(4, 128), 256, 0, stream>>>(qb, kb, v4);
  gemm_bt1<<<dim3(1024 / 128, 8192 / 128), 256, 0, stream>>>(qb, woT, b_out,
                                                             1024, 1024, out);
}